// Round 1
// baseline (1488.834 us; speedup 1.0000x reference)
//
#include <hip/hip_runtime.h>

#define N_NODES 50000
#define N_EDGES 800000
constexpr float BN_EPS = 1e-5f;

// ---------------- degree / CSR build ----------------

__global__ void count_deg(const int* __restrict__ dst, int* cnts) {
    int e = blockIdx.x * 256 + threadIdx.x;
    if (e < N_EDGES) atomicAdd(&cnts[dst[e]], 1);
}

__global__ void finalize_deg(const int* __restrict__ cnts, float* __restrict__ dinv,
                             float* __restrict__ invdeg) {
    int i = blockIdx.x * 256 + threadIdx.x;
    if (i < N_NODES) {
        float d = (float)cnts[i] + 1.0f;
        dinv[i] = rsqrtf(d);
        invdeg[i] = 1.0f / d;
    }
}

__global__ __launch_bounds__(1024)
void scan_offsets(const int* __restrict__ counts, int* __restrict__ offs,
                  int* __restrict__ cursor) {
    __shared__ int wsum[16];
    __shared__ int btot;
    __shared__ int carry;
    int tid = threadIdx.x, lane = tid & 63, wid = tid >> 6;
    if (tid == 0) carry = 0;
    __syncthreads();
    for (int base = 0; base < N_NODES; base += 1024) {
        int i = base + tid;
        int v = (i < N_NODES) ? counts[i] : 0;
        int s = v;
        #pragma unroll
        for (int d = 1; d < 64; d <<= 1) {
            int t = __shfl_up(s, d, 64);
            if (lane >= d) s += t;
        }
        if (lane == 63) wsum[wid] = s;
        __syncthreads();
        if (tid == 0) {
            int acc = 0;
            #pragma unroll
            for (int w = 0; w < 16; ++w) { int t = wsum[w]; wsum[w] = acc; acc += t; }
            btot = acc;
        }
        __syncthreads();
        int excl = carry + wsum[wid] + (s - v);
        if (i < N_NODES) { offs[i] = excl; cursor[i] = excl; }
        __syncthreads();
        if (tid == 0) carry += btot;
    }
}

__global__ void fill_csr(const int* __restrict__ src, const int* __restrict__ dst,
                         const float* __restrict__ dinv, int* cursor,
                         int* __restrict__ csrc, float* __restrict__ cnorm) {
    int e = blockIdx.x * 256 + threadIdx.x;
    if (e < N_EDGES) {
        int s = src[e], d = dst[e];
        int pos = atomicAdd(&cursor[d], 1);
        csrc[pos] = s;
        cnorm[pos] = dinv[s] * dinv[d];
    }
}

// ---------------- GEMM: H = X @ W  (f32, 4x4 register block, W+X in LDS) ----------------

template<int FI, int FO>
__global__ __launch_bounds__(256)
void gemm_tile(const float* __restrict__ X, const float* __restrict__ W,
               float* __restrict__ H) {
    constexpr int CT = FO / 4;        // col-threads
    constexpr int RT = 256 / CT;      // row-threads
    constexpr int ROWS = RT * 4;      // rows per tile
    __shared__ float Ws[FI * FO];
    __shared__ float xs[ROWS * FI];
    for (int i = threadIdx.x * 4; i < FI * FO; i += 1024)
        *(float4*)&Ws[i] = *(const float4*)&W[i];
    const int ct = threadIdx.x % CT, rt = threadIdx.x / CT;
    const int ntiles = (N_NODES + ROWS - 1) / ROWS;
    for (int tile = blockIdx.x; tile < ntiles; tile += gridDim.x) {
        const int base = tile * ROWS;
        __syncthreads();   // covers Ws on iter 0, protects xs otherwise
        for (int t = threadIdx.x; t < ROWS * FI / 4; t += 256) {
            int r = t / (FI / 4), k4 = (t % (FI / 4)) * 4;
            int gr = base + r;
            float4 v = (gr < N_NODES) ? *(const float4*)&X[(size_t)gr * FI + k4]
                                      : make_float4(0.f, 0.f, 0.f, 0.f);
            *(float4*)&xs[r * FI + k4] = v;
        }
        __syncthreads();
        float acc[4][4] = {};
        #pragma unroll 2
        for (int k4 = 0; k4 < FI; k4 += 4) {
            float4 xv[4], wv[4];
            #pragma unroll
            for (int ri = 0; ri < 4; ++ri)
                xv[ri] = *(const float4*)&xs[(rt * 4 + ri) * FI + k4];
            #pragma unroll
            for (int j = 0; j < 4; ++j)
                wv[j] = *(const float4*)&Ws[(k4 + j) * FO + ct * 4];
            #pragma unroll
            for (int ri = 0; ri < 4; ++ri) {
                #pragma unroll
                for (int j = 0; j < 4; ++j) {
                    float xk = ((const float*)&xv[ri])[j];
                    acc[ri][0] = fmaf(xk, wv[j].x, acc[ri][0]);
                    acc[ri][1] = fmaf(xk, wv[j].y, acc[ri][1]);
                    acc[ri][2] = fmaf(xk, wv[j].z, acc[ri][2]);
                    acc[ri][3] = fmaf(xk, wv[j].w, acc[ri][3]);
                }
            }
        }
        #pragma unroll
        for (int ri = 0; ri < 4; ++ri) {
            int row = base + rt * 4 + ri;
            if (row < N_NODES)
                *(float4*)&H[(size_t)row * FO + ct * 4] =
                    make_float4(acc[ri][0], acc[ri][1], acc[ri][2], acc[ri][3]);
        }
    }
}

// ---------------- aggregation (CSR gather) + bias + self-loop + fused BN stats ----------------

template<int FO>
__global__ __launch_bounds__(256)
void aggregate_bn(const float* __restrict__ H, const int* __restrict__ offs,
                  const int* __restrict__ cnt, const int* __restrict__ csrc,
                  const float* __restrict__ cnorm, const float* __restrict__ invdeg,
                  const float* __restrict__ bias, float* __restrict__ out,
                  float* __restrict__ stats) {
    constexpr int LPR = FO / 4;       // lanes per row
    constexpr int RPB = 256 / LPR;    // rows per block-iter
    const int lt = threadIdx.x % LPR;
    const int sub = threadIdx.x / LPR;
    const int o4 = lt * 4;
    const float4 b4 = *(const float4*)&bias[o4];
    float s[4] = {0, 0, 0, 0}, s2[4] = {0, 0, 0, 0};
    const float4* H4 = (const float4*)H;
    float4* out4 = (float4*)out;
    for (int r = blockIdx.x * RPB + sub; r < N_NODES; r += gridDim.x * RPB) {
        float idg = invdeg[r];
        float4 h = H4[(size_t)r * LPR + lt];
        float a0 = fmaf(h.x, idg, b4.x), a1 = fmaf(h.y, idg, b4.y);
        float a2 = fmaf(h.z, idg, b4.z), a3 = fmaf(h.w, idg, b4.w);
        int e = offs[r], en = e + cnt[r];
        for (; e < en; ++e) {
            int srow = csrc[e];
            float w = cnorm[e];
            float4 hv = H4[(size_t)srow * LPR + lt];
            a0 = fmaf(hv.x, w, a0); a1 = fmaf(hv.y, w, a1);
            a2 = fmaf(hv.z, w, a2); a3 = fmaf(hv.w, w, a3);
        }
        out4[(size_t)r * LPR + lt] = make_float4(a0, a1, a2, a3);
        s[0] += a0; s2[0] += a0 * a0;
        s[1] += a1; s2[1] += a1 * a1;
        s[2] += a2; s2[2] += a2 * a2;
        s[3] += a3; s2[3] += a3 * a3;
    }
    __shared__ float ls[256][4], ls2[256][4];
    #pragma unroll
    for (int j = 0; j < 4; ++j) { ls[threadIdx.x][j] = s[j]; ls2[threadIdx.x][j] = s2[j]; }
    __syncthreads();
    if (sub == 0) {
        for (int t = 1; t < RPB; ++t) {
            #pragma unroll
            for (int j = 0; j < 4; ++j) {
                s[j] += ls[t * LPR + lt][j];
                s2[j] += ls2[t * LPR + lt][j];
            }
        }
        #pragma unroll
        for (int j = 0; j < 4; ++j) {
            atomicAdd(&stats[o4 + j], s[j]);
            atomicAdd(&stats[FO + o4 + j], s2[j]);
        }
    }
}

// ---------------- BatchNorm normalize (+optional ReLU) ----------------

template<int FO, bool RELU>
__global__ __launch_bounds__(256)
void bn_norm(const float* __restrict__ X, const float* __restrict__ stats,
             const float* __restrict__ g, const float* __restrict__ be,
             float* __restrict__ Y) {
    constexpr float invN = 1.0f / (float)N_NODES;
    const int total4 = N_NODES * FO / 4;
    for (int idx = blockIdx.x * 256 + threadIdx.x; idx < total4; idx += gridDim.x * 256) {
        int o4 = (idx * 4) & (FO - 1);
        float4 x = ((const float4*)X)[idx];
        float y[4];
        #pragma unroll
        for (int j = 0; j < 4; ++j) {
            int o = o4 + j;
            float m = stats[o] * invN;
            float v = stats[FO + o] * invN - m * m;
            float istd = rsqrtf(v + BN_EPS);
            float val = ((&x.x)[j] - m) * istd * g[o] + be[o];
            if (RELU) val = fmaxf(val, 0.f);
            y[j] = val;
        }
        ((float4*)Y)[idx] = make_float4(y[0], y[1], y[2], y[3]);
    }
}

// ---------------- driver ----------------

extern "C" void kernel_launch(void* const* d_in, const int* in_sizes, int n_in,
                              void* d_out, int out_size, void* d_ws, size_t ws_size,
                              hipStream_t stream) {
    const float* x  = (const float*)d_in[0];
    const int* ei   = (const int*)d_in[1];
    const int* src  = ei;
    const int* dst  = ei + N_EDGES;

    size_t off = 0;
    auto alloc = [&](size_t bytes) -> void* {
        void* p = (char*)d_ws + off;
        off += (bytes + 255) & ~(size_t)255;
        return p;
    };
    int*   counts = (int*)  alloc((size_t)N_NODES * 4);
    int*   offs   = (int*)  alloc((size_t)N_NODES * 4);
    int*   cursor = (int*)  alloc((size_t)N_NODES * 4);
    float* dinv   = (float*)alloc((size_t)N_NODES * 4);
    float* invdeg = (float*)alloc((size_t)N_NODES * 4);
    int*   csrc   = (int*)  alloc((size_t)N_EDGES * 4);
    float* cnorm  = (float*)alloc((size_t)N_EDGES * 4);
    float* stats  = (float*)alloc(6 * 256 * 4);
    float* H      = (float*)alloc((size_t)N_NODES * 128 * 4);
    float* A0     = (float*)alloc((size_t)N_NODES * 128 * 4);
    float* A1     = (float*)alloc((size_t)N_NODES * 128 * 4);

    hipMemsetAsync(counts, 0, (size_t)N_NODES * 4, stream);
    hipMemsetAsync(stats, 0, 6 * 256 * 4, stream);

    count_deg<<<(N_EDGES + 255) / 256, 256, 0, stream>>>(dst, counts);
    finalize_deg<<<(N_NODES + 255) / 256, 256, 0, stream>>>(counts, dinv, invdeg);
    scan_offsets<<<1, 1024, 0, stream>>>(counts, offs, cursor);
    fill_csr<<<(N_EDGES + 255) / 256, 256, 0, stream>>>(src, dst, dinv, cursor, csrc, cnorm);

    struct LayerDef { int fi, fo; bool relu; };
    const LayerDef L[6] = {
        {128, 128, true}, {128, 128, true}, {128, 64, false},
        {64, 128, true},  {128, 128, true}, {128, 128, false}
    };
    float* outbuf[6] = {A0, A1, A0, A1, A0, (float*)d_out};

    const float* in = x;
    for (int j = 0; j < 6; ++j) {
        const float* W  = (const float*)d_in[2 + 4 * j];
        const float* b  = (const float*)d_in[3 + 4 * j];
        const float* g  = (const float*)d_in[4 + 4 * j];
        const float* be = (const float*)d_in[5 + 4 * j];
        float* ob = outbuf[j];
        float* st = stats + j * 256;

        if (L[j].fi == 128 && L[j].fo == 128)
            gemm_tile<128, 128><<<512, 256, 0, stream>>>(in, W, H);
        else if (L[j].fi == 128 && L[j].fo == 64)
            gemm_tile<128, 64><<<512, 256, 0, stream>>>(in, W, H);
        else
            gemm_tile<64, 128><<<512, 256, 0, stream>>>(in, W, H);

        if (L[j].fo == 128)
            aggregate_bn<128><<<512, 256, 0, stream>>>(H, offs, counts, csrc, cnorm,
                                                       invdeg, b, ob, st);
        else
            aggregate_bn<64><<<512, 256, 0, stream>>>(H, offs, counts, csrc, cnorm,
                                                      invdeg, b, ob, st);

        if (L[j].fo == 128) {
            if (L[j].relu)
                bn_norm<128, true><<<2048, 256, 0, stream>>>(ob, st, g, be, ob);
            else
                bn_norm<128, false><<<2048, 256, 0, stream>>>(ob, st, g, be, ob);
        } else {
            bn_norm<64, false><<<2048, 256, 0, stream>>>(ob, st, g, be, ob);
        }
        in = ob;
    }
}